// Round 1
// baseline (4184.879 us; speedup 1.0000x reference)
//
#include <hip/hip_runtime.h>

#define KSEG 10000

// ---------------- histogram + event count ----------------
__global__ void hist_kernel(const int* __restrict__ dur, const int* __restrict__ events,
                            int* __restrict__ counts, int* __restrict__ ev_total, int N) {
    int j = blockIdx.x * blockDim.x + threadIdx.x;
    int ev = 0;
    if (j < N) {
        atomicAdd(&counts[dur[j]], 1);
        ev = events[j];
    }
    unsigned long long m = __ballot(ev != 0);
    if ((threadIdx.x & 63) == 0 && m != 0ull)
        atomicAdd(ev_total, (int)__popcll(m));
}

// ---------------- exclusive prefix scan over K bins (single block) ----------------
__global__ void scan_kernel(const int* __restrict__ counts, int* __restrict__ cum, int K) {
    __shared__ int sm[1024];
    __shared__ int carry_s;
    int tid = threadIdx.x;
    if (tid == 0) carry_s = 0;
    __syncthreads();
    for (int base = 0; base < K; base += 1024) {
        int v = (base + tid < K) ? counts[base + tid] : 0;
        sm[tid] = v;
        __syncthreads();
        for (int off = 1; off < 1024; off <<= 1) {
            int t = (tid >= off) ? sm[tid - off] : 0;
            __syncthreads();
            sm[tid] += t;
            __syncthreads();
        }
        int carry = carry_s;
        if (base + tid < K) cum[base + tid] = carry + sm[tid] - v;  // exclusive
        __syncthreads();
        if (tid == 1023) carry_s = carry + sm[1023];
        __syncthreads();
    }
    if (tid == 0) cum[K] = carry_s;
}

// ---------------- arbitrary-order scatter into group slots ----------------
__global__ void scatter_kernel(const int* __restrict__ dur, const int* __restrict__ cum,
                               int* __restrict__ cursor, int* __restrict__ G, int N) {
    int j = blockIdx.x * blockDim.x + threadIdx.x;
    if (j >= N) return;
    int t = dur[j];
    int pos = atomicAdd(&cursor[t], 1);
    G[cum[t] + pos] = j;
}

// ---------------- per-group ascending sort (restores stability) ----------------
__global__ void sort_groups(int* __restrict__ G, const int* __restrict__ cum) {
    int t = blockIdx.x;
    int a = cum[t], b = cum[t + 1];
    int c = b - a;
    if (c <= 1) return;
    __shared__ int sm[4096];
    if (c <= 4096) {
        int n = 1;
        while (n < c) n <<= 1;
        for (int i = threadIdx.x; i < n; i += blockDim.x)
            sm[i] = (i < c) ? G[a + i] : 0x7fffffff;
        __syncthreads();
        for (int k = 2; k <= n; k <<= 1) {
            for (int j = k >> 1; j > 0; j >>= 1) {
                for (int i = threadIdx.x; i < n; i += blockDim.x) {
                    int l = i ^ j;
                    if (l > i) {
                        int vi = sm[i], vl = sm[l];
                        bool up = ((i & k) == 0);
                        if ((vi > vl) == up) { sm[i] = vl; sm[l] = vi; }
                    }
                }
                __syncthreads();
            }
        }
        for (int i = threadIdx.x; i < c; i += blockDim.x) G[a + i] = sm[i];
    } else {
        // fallback (never expected for Poisson(800) groups): odd-even transposition in global
        for (int it = 0; it < c; ++it) {
            int start = it & 1;
            for (int i = start + 2 * (int)threadIdx.x; i + 1 < c; i += 2 * (int)blockDim.x) {
                int x = G[a + i], y = G[a + i + 1];
                if (x > y) { G[a + i] = y; G[a + i + 1] = x; }
            }
            __syncthreads();
        }
    }
}

// ---------------- segment sums: expg_sum / ev_sum keyed by ORIGINAL durations ----------------
// expg_sum[t] = sum_{j: dur[j]==t} exp(log_h[idx_desc[j]])
// idx_desc[p]: bin tb = dur[G[N-1-p]]; r = p - (N - cum[tb+1]); -> G[cum[tb]+r]
__global__ void sums_kernel(const float* __restrict__ log_h, const int* __restrict__ dur,
                            const int* __restrict__ events, const int* __restrict__ G,
                            const int* __restrict__ cum, float* __restrict__ expg,
                            float* __restrict__ evs, int N) {
    int j = blockIdx.x * blockDim.x + threadIdx.x;
    if (j >= N) return;
    int tb = dur[G[N - 1 - j]];
    int r = j - (N - cum[tb + 1]);
    int idx = G[cum[tb] + r];
    int tseg = dur[j];
    atomicAdd(&expg[tseg], expf(log_h[idx]));
    atomicAdd(&evs[tseg], (float)events[idx]);
}

// ---------------- risk suffix-sum + baseline hazard ----------------
__global__ void baseline_kernel(const float* __restrict__ expg, const float* __restrict__ evs,
                                float* __restrict__ base, int K) {
    __shared__ float sm[1024];
    __shared__ float carry_s;
    int tid = threadIdx.x;
    if (tid == 0) carry_s = 0.f;
    __syncthreads();
    for (int b = 0; b < K; b += 1024) {
        int u = b + tid;          // reversed index
        int t = K - 1 - u;        // actual bin
        float v = (u < K) ? expg[t] : 0.f;
        sm[tid] = v;
        __syncthreads();
        for (int off = 1; off < 1024; off <<= 1) {
            float x = (tid >= off) ? sm[tid - off] : 0.f;
            __syncthreads();
            sm[tid] += x;
            __syncthreads();
        }
        float carry = carry_s;
        if (u < K) {
            float risk = carry + sm[tid];  // inclusive suffix sum over bins >= t
            base[t] = (risk > 0.f) ? evs[t] / risk : 0.f;
        }
        __syncthreads();
        if (tid == 1023) carry_s = carry + sm[1023];
        __syncthreads();
    }
}

// ---------------- MSE over ascending ranks p ----------------
// term(p) = (base[dur[G[p]]] * exp(log_h[idx_desc[p]]) - events[idx_desc[G[p]]])^2
__global__ void mse_kernel(const float* __restrict__ log_h, const int* __restrict__ dur,
                           const int* __restrict__ events, const int* __restrict__ G,
                           const int* __restrict__ cum, const float* __restrict__ base,
                           double* __restrict__ acc, int N) {
    int p = blockIdx.x * blockDim.x + threadIdx.x;
    double term = 0.0;
    if (p < N) {
        int x = G[p];                                   // idx_asc[p]
        int t0 = dur[x];                                // sorted_dur[p]
        int t1 = dur[G[N - 1 - p]];                     // bin of desc-rank p
        int i1 = G[cum[t1] + (p - (N - cum[t1 + 1]))];  // idx_desc[p]
        int t2 = dur[G[N - 1 - x]];                     // bin of desc-rank x
        int i2 = G[cum[t2] + (x - (N - cum[t2 + 1]))];  // idx_desc[idx_asc[p]]
        float pred = base[t0] * expf(log_h[i1]);
        float d = pred - (float)events[i2];
        term = (double)d * (double)d;
    }
    __shared__ double sm[256];
    sm[threadIdx.x] = term;
    __syncthreads();
    for (int o = 128; o > 0; o >>= 1) {
        if ((int)threadIdx.x < o) sm[threadIdx.x] += sm[threadIdx.x + o];
        __syncthreads();
    }
    if (threadIdx.x == 0) atomicAdd(acc, sm[0]);
}

__global__ void final_kernel(const double* __restrict__ acc, const int* __restrict__ ev_total,
                             float* __restrict__ out, int N) {
    out[0] = (*ev_total == 0) ? 0.0f : (float)(*acc / (double)N);
}

extern "C" void kernel_launch(void* const* d_in, const int* in_sizes, int n_in,
                              void* d_out, int out_size, void* d_ws, size_t ws_size,
                              hipStream_t stream) {
    const float* log_h = (const float*)d_in[0];
    const int* dur     = (const int*)d_in[1];
    const int* events  = (const int*)d_in[2];
    int N = in_sizes[0];
    float* out = (float*)d_out;

    char* ws = (char*)d_ws;
    size_t off = 0;
    auto alloc = [&](size_t bytes) -> char* {
        char* p = ws + off;
        off = (off + bytes + 255) & ~(size_t)255;
        return p;
    };
    int*    counts   = (int*)alloc(KSEG * 4);
    int*    cursor   = (int*)alloc(KSEG * 4);
    float*  expg     = (float*)alloc(KSEG * 4);
    float*  evs      = (float*)alloc(KSEG * 4);
    int*    ev_total = (int*)alloc(4);
    double* acc      = (double*)alloc(8);
    size_t zero_bytes = off;  // everything above must start at 0 each call
    int*    cum  = (int*)alloc((KSEG + 1) * 4);
    float*  base = (float*)alloc(KSEG * 4);
    int*    G    = (int*)alloc((size_t)N * 4);
    (void)ws_size;

    hipMemsetAsync(d_ws, 0, zero_bytes, stream);

    int blocks = (N + 255) / 256;
    hist_kernel<<<blocks, 256, 0, stream>>>(dur, events, counts, ev_total, N);
    scan_kernel<<<1, 1024, 0, stream>>>(counts, cum, KSEG);
    scatter_kernel<<<blocks, 256, 0, stream>>>(dur, cum, cursor, G, N);
    sort_groups<<<KSEG, 256, 0, stream>>>(G, cum);
    sums_kernel<<<blocks, 256, 0, stream>>>(log_h, dur, events, G, cum, expg, evs, N);
    baseline_kernel<<<1, 1024, 0, stream>>>(expg, evs, base, KSEG);
    mse_kernel<<<blocks, 256, 0, stream>>>(log_h, dur, events, G, cum, base, acc, N);
    final_kernel<<<1, 1, 0, stream>>>(acc, ev_total, out, N);
}

// Round 2
// 1981.156 us; speedup vs baseline: 2.1123x; 2.1123x over previous
//
#include <hip/hip_runtime.h>

#define KSEG 10000
#define NBLK 256   // counting-sort blocks (contiguous chunks)

// ---------------- per-block LDS histogram + event total ----------------
__global__ __launch_bounds__(512) void hist_blocks(const int* __restrict__ dur,
                                                   const int* __restrict__ events,
                                                   int* __restrict__ blockhist,
                                                   int* __restrict__ ev_total,
                                                   int N, int chunk) {
    __shared__ int h[KSEG];
    __shared__ int red[512];
    for (int i = threadIdx.x; i < KSEG; i += blockDim.x) h[i] = 0;
    __syncthreads();
    int b = blockIdx.x;
    int s = b * chunk, e = min(N, s + chunk);
    int evc = 0;
    for (int j = s + threadIdx.x; j < e; j += blockDim.x) {
        atomicAdd(&h[dur[j]], 1);
        evc += events[j];
    }
    __syncthreads();
    for (int i = threadIdx.x; i < KSEG; i += blockDim.x)
        blockhist[(size_t)b * KSEG + i] = h[i];
    red[threadIdx.x] = evc;
    __syncthreads();
    for (int o = (int)blockDim.x >> 1; o > 0; o >>= 1) {
        if ((int)threadIdx.x < o) red[threadIdx.x] += red[threadIdx.x + o];
        __syncthreads();
    }
    if (threadIdx.x == 0) atomicAdd(ev_total, red[0]);
}

// ---------------- column scan: per-bin running sum over blocks ----------------
__global__ void colscan(const int* __restrict__ blockhist, int* __restrict__ blockbase,
                        int* __restrict__ counts, int B) {
    int t = blockIdx.x * blockDim.x + threadIdx.x;
    if (t >= KSEG) return;
    int run = 0;
    for (int b = 0; b < B; ++b) {
        int v = blockhist[(size_t)b * KSEG + t];
        blockbase[(size_t)b * KSEG + t] = run;
        run += v;
    }
    counts[t] = run;
}

// ---------------- exclusive prefix scan over K bins (single block) ----------------
__global__ void scan_kernel(const int* __restrict__ counts, int* __restrict__ cum, int K) {
    __shared__ int sm[1024];
    __shared__ int carry_s;
    int tid = threadIdx.x;
    if (tid == 0) carry_s = 0;
    __syncthreads();
    for (int base = 0; base < K; base += 1024) {
        int v = (base + tid < K) ? counts[base + tid] : 0;
        sm[tid] = v;
        __syncthreads();
        for (int off = 1; off < 1024; off <<= 1) {
            int t = (tid >= off) ? sm[tid - off] : 0;
            __syncthreads();
            sm[tid] += t;
            __syncthreads();
        }
        int carry = carry_s;
        if (base + tid < K) cum[base + tid] = carry + sm[tid] - v;  // exclusive
        __syncthreads();
        if (tid == 1023) carry_s = carry + sm[1023];
        __syncthreads();
    }
    if (tid == 0) cum[K] = carry_s;
}

// ---------------- scatter with LDS-only cursors ----------------
__global__ __launch_bounds__(512) void scatter2(const int* __restrict__ dur,
                                                const int* __restrict__ cum,
                                                const int* __restrict__ blockbase,
                                                int* __restrict__ G, int N, int chunk) {
    __shared__ int cur[KSEG];
    int b = blockIdx.x;
    for (int i = threadIdx.x; i < KSEG; i += blockDim.x)
        cur[i] = cum[i] + blockbase[(size_t)b * KSEG + i];
    __syncthreads();
    int s = b * chunk, e = min(N, s + chunk);
    for (int j = s + threadIdx.x; j < e; j += blockDim.x) {
        int t = dur[j];
        int pos = atomicAdd(&cur[t], 1);
        G[pos] = j;
    }
}

// ---------------- per-group ascending sort (restores stability) ----------------
__global__ void sort_groups(int* __restrict__ G, const int* __restrict__ cum) {
    int t = blockIdx.x;
    int a = cum[t], b = cum[t + 1];
    int c = b - a;
    if (c <= 1) return;
    __shared__ int sm[4096];
    if (c <= 4096) {
        int n = 1;
        while (n < c) n <<= 1;
        for (int i = threadIdx.x; i < n; i += blockDim.x)
            sm[i] = (i < c) ? G[a + i] : 0x7fffffff;
        __syncthreads();
        for (int k = 2; k <= n; k <<= 1) {
            for (int j = k >> 1; j > 0; j >>= 1) {
                for (int i = threadIdx.x; i < n; i += blockDim.x) {
                    int l = i ^ j;
                    if (l > i) {
                        int vi = sm[i], vl = sm[l];
                        bool up = ((i & k) == 0);
                        if ((vi > vl) == up) { sm[i] = vl; sm[l] = vi; }
                    }
                }
                __syncthreads();
            }
        }
        for (int i = threadIdx.x; i < c; i += blockDim.x) G[a + i] = sm[i];
    } else {
        for (int it = 0; it < c; ++it) {
            int start = it & 1;
            for (int i = start + 2 * (int)threadIdx.x; i + 1 < c; i += 2 * (int)blockDim.x) {
                int x = G[a + i], y = G[a + i + 1];
                if (x > y) { G[a + i] = y; G[a + i + 1] = x; }
            }
            __syncthreads();
        }
    }
}

// ---------------- segment sums via LDS float histograms ----------------
// expg_sum[t] = sum_{j: dur[j]==t} exp(log_h[idx_desc[j]])
// idx_desc[p]: tb = dur[G[N-1-p]]; r = p - (N - cum[tb+1]); -> G[cum[tb]+r]
__global__ __launch_bounds__(512) void sums2(const float* __restrict__ log_h,
                                             const int* __restrict__ dur,
                                             const int* __restrict__ events,
                                             const int* __restrict__ G,
                                             const int* __restrict__ cum,
                                             float* __restrict__ expg_part,
                                             float* __restrict__ evs_part,
                                             int N, int chunk) {
    __shared__ float he[KSEG];
    __shared__ float hv[KSEG];
    for (int i = threadIdx.x; i < KSEG; i += blockDim.x) { he[i] = 0.f; hv[i] = 0.f; }
    __syncthreads();
    int b = blockIdx.x;
    int s = b * chunk, e = min(N, s + chunk);
    for (int j = s + threadIdx.x; j < e; j += blockDim.x) {
        int tb = dur[G[N - 1 - j]];
        int r = j - (N - cum[tb + 1]);
        int idx = G[cum[tb] + r];
        int tseg = dur[j];
        atomicAdd(&he[tseg], expf(log_h[idx]));
        atomicAdd(&hv[tseg], (float)events[idx]);
    }
    __syncthreads();
    for (int i = threadIdx.x; i < KSEG; i += blockDim.x) {
        expg_part[(size_t)b * KSEG + i] = he[i];
        evs_part[(size_t)b * KSEG + i] = hv[i];
    }
}

__global__ void reduce_sums(const float* __restrict__ expg_part,
                            const float* __restrict__ evs_part,
                            float* __restrict__ expg, float* __restrict__ evs, int B) {
    int t = blockIdx.x * blockDim.x + threadIdx.x;
    if (t >= KSEG) return;
    float a = 0.f, v = 0.f;
    for (int b = 0; b < B; ++b) {
        a += expg_part[(size_t)b * KSEG + t];
        v += evs_part[(size_t)b * KSEG + t];
    }
    expg[t] = a;
    evs[t] = v;
}

// ---------------- risk suffix-sum + baseline hazard ----------------
__global__ void baseline_kernel(const float* __restrict__ expg, const float* __restrict__ evs,
                                float* __restrict__ base, int K) {
    __shared__ float sm[1024];
    __shared__ float carry_s;
    int tid = threadIdx.x;
    if (tid == 0) carry_s = 0.f;
    __syncthreads();
    for (int b = 0; b < K; b += 1024) {
        int u = b + tid;
        int t = K - 1 - u;
        float v = (u < K) ? expg[t] : 0.f;
        sm[tid] = v;
        __syncthreads();
        for (int off = 1; off < 1024; off <<= 1) {
            float x = (tid >= off) ? sm[tid - off] : 0.f;
            __syncthreads();
            sm[tid] += x;
            __syncthreads();
        }
        float carry = carry_s;
        if (u < K) {
            float risk = carry + sm[tid];
            base[t] = (risk > 0.f) ? evs[t] / risk : 0.f;
        }
        __syncthreads();
        if (tid == 1023) carry_s = carry + sm[1023];
        __syncthreads();
    }
}

// ---------------- MSE over ascending ranks p (grid-stride) ----------------
__global__ __launch_bounds__(256) void mse2(const float* __restrict__ log_h,
                                            const int* __restrict__ dur,
                                            const int* __restrict__ events,
                                            const int* __restrict__ G,
                                            const int* __restrict__ cum,
                                            const float* __restrict__ base,
                                            double* __restrict__ acc, int N) {
    int stride = gridDim.x * blockDim.x;
    double term = 0.0;
    for (int p = blockIdx.x * blockDim.x + threadIdx.x; p < N; p += stride) {
        int x = G[p];                                   // idx_asc[p]
        int t0 = dur[x];                                // sorted_dur[p]
        int t1 = dur[G[N - 1 - p]];                     // bin of desc-rank p
        int i1 = G[cum[t1] + (p - (N - cum[t1 + 1]))];  // idx_desc[p]
        int t2 = dur[G[N - 1 - x]];                     // bin of desc-rank x
        int i2 = G[cum[t2] + (x - (N - cum[t2 + 1]))];  // idx_desc[idx_asc[p]]
        float pred = base[t0] * expf(log_h[i1]);
        float d = pred - (float)events[i2];
        term += (double)d * (double)d;
    }
    __shared__ double sm[256];
    sm[threadIdx.x] = term;
    __syncthreads();
    for (int o = 128; o > 0; o >>= 1) {
        if ((int)threadIdx.x < o) sm[threadIdx.x] += sm[threadIdx.x + o];
        __syncthreads();
    }
    if (threadIdx.x == 0) atomicAdd(acc, sm[0]);
}

__global__ void final_kernel(const double* __restrict__ acc, const int* __restrict__ ev_total,
                             float* __restrict__ out, int N) {
    out[0] = (*ev_total == 0) ? 0.0f : (float)(*acc / (double)N);
}

extern "C" void kernel_launch(void* const* d_in, const int* in_sizes, int n_in,
                              void* d_out, int out_size, void* d_ws, size_t ws_size,
                              hipStream_t stream) {
    const float* log_h = (const float*)d_in[0];
    const int* dur     = (const int*)d_in[1];
    const int* events  = (const int*)d_in[2];
    int N = in_sizes[0];
    float* out = (float*)d_out;

    char* ws = (char*)d_ws;
    size_t off = 0;
    auto alloc = [&](size_t bytes) -> char* {
        char* p = ws + off;
        off = (off + bytes + 255) & ~(size_t)255;
        return p;
    };
    double* acc      = (double*)alloc(8);
    int*    ev_total = (int*)alloc(4);
    size_t zero_bytes = off;
    int*    counts    = (int*)alloc(KSEG * 4);
    int*    cum       = (int*)alloc((KSEG + 1) * 4);
    float*  expg      = (float*)alloc(KSEG * 4);
    float*  evs       = (float*)alloc(KSEG * 4);
    float*  base      = (float*)alloc(KSEG * 4);
    int*    blockhist = (int*)alloc((size_t)NBLK * KSEG * 4);  // reused as expg_part
    int*    blockbase = (int*)alloc((size_t)NBLK * KSEG * 4);  // reused as evs_part
    int*    G         = (int*)alloc((size_t)N * 4);
    (void)ws_size;

    int chunk = (N + NBLK - 1) / NBLK;

    hipMemsetAsync(d_ws, 0, zero_bytes, stream);

    hist_blocks<<<NBLK, 512, 0, stream>>>(dur, events, blockhist, ev_total, N, chunk);
    colscan<<<(KSEG + 255) / 256, 256, 0, stream>>>(blockhist, blockbase, counts, NBLK);
    scan_kernel<<<1, 1024, 0, stream>>>(counts, cum, KSEG);
    scatter2<<<NBLK, 512, 0, stream>>>(dur, cum, blockbase, G, N, chunk);
    sort_groups<<<KSEG, 256, 0, stream>>>(G, cum);
    sums2<<<NBLK, 512, 0, stream>>>(log_h, dur, events, G, cum,
                                    (float*)blockhist, (float*)blockbase, N, chunk);
    reduce_sums<<<(KSEG + 255) / 256, 256, 0, stream>>>((const float*)blockhist,
                                                        (const float*)blockbase, expg, evs, NBLK);
    baseline_kernel<<<1, 1024, 0, stream>>>(expg, evs, base, KSEG);
    mse2<<<4096, 256, 0, stream>>>(log_h, dur, events, G, cum, base, acc, N);
    final_kernel<<<1, 1, 0, stream>>>(acc, ev_total, out, N);
}

// Round 3
// 1137.579 us; speedup vs baseline: 3.6788x; 1.7416x over previous
//
#include <hip/hip_runtime.h>

#define KSEG 10000
#define NBLK 256   // counting-sort blocks (contiguous chunks)

// ---------------- per-block LDS histogram of durations ----------------
__global__ __launch_bounds__(512) void hist_blocks(const int* __restrict__ dur,
                                                   int* __restrict__ blockhist,
                                                   int N, int chunk) {
    __shared__ int h[KSEG];
    for (int i = threadIdx.x; i < KSEG; i += blockDim.x) h[i] = 0;
    __syncthreads();
    int b = blockIdx.x;
    int s = b * chunk, e = min(N, s + chunk);
    for (int j = s + threadIdx.x; j < e; j += blockDim.x)
        atomicAdd(&h[dur[j]], 1);
    __syncthreads();
    for (int i = threadIdx.x; i < KSEG; i += blockDim.x)
        blockhist[(size_t)b * KSEG + i] = h[i];
}

// ---------------- column scan: per-bin running sum over blocks ----------------
__global__ void colscan(const int* __restrict__ blockhist, int* __restrict__ blockbase,
                        int* __restrict__ counts, int B) {
    int t = blockIdx.x * blockDim.x + threadIdx.x;
    if (t >= KSEG) return;
    int run = 0;
    for (int b = 0; b < B; ++b) {
        int v = blockhist[(size_t)b * KSEG + t];
        blockbase[(size_t)b * KSEG + t] = run;
        run += v;
    }
    counts[t] = run;
}

// ---------------- exclusive prefix scan over K bins (single block) ----------------
__global__ void scan_kernel(const int* __restrict__ counts, int* __restrict__ cum, int K) {
    __shared__ int sm[1024];
    __shared__ int carry_s;
    int tid = threadIdx.x;
    if (tid == 0) carry_s = 0;
    __syncthreads();
    for (int base = 0; base < K; base += 1024) {
        int v = (base + tid < K) ? counts[base + tid] : 0;
        sm[tid] = v;
        __syncthreads();
        for (int off = 1; off < 1024; off <<= 1) {
            int t = (tid >= off) ? sm[tid - off] : 0;
            __syncthreads();
            sm[tid] += t;
            __syncthreads();
        }
        int carry = carry_s;
        if (base + tid < K) cum[base + tid] = carry + sm[tid] - v;  // exclusive
        __syncthreads();
        if (tid == 1023) carry_s = carry + sm[1023];
        __syncthreads();
    }
    if (tid == 0) cum[K] = carry_s;
}

// ---------------- scatter with LDS-only cursors ----------------
__global__ __launch_bounds__(512) void scatter2(const int* __restrict__ dur,
                                                const int* __restrict__ cum,
                                                const int* __restrict__ blockbase,
                                                int* __restrict__ G, int N, int chunk) {
    __shared__ int cur[KSEG];
    int b = blockIdx.x;
    for (int i = threadIdx.x; i < KSEG; i += blockDim.x)
        cur[i] = cum[i] + blockbase[(size_t)b * KSEG + i];
    __syncthreads();
    int s = b * chunk, e = min(N, s + chunk);
    for (int j = s + threadIdx.x; j < e; j += blockDim.x) {
        int t = dur[j];
        int pos = atomicAdd(&cur[t], 1);
        G[pos] = j;
    }
}

// ---------------- per-group ascending sort (restores stability) ----------------
__global__ void sort_groups(int* __restrict__ G, const int* __restrict__ cum) {
    int t = blockIdx.x;
    int a = cum[t], b = cum[t + 1];
    int c = b - a;
    if (c <= 1) return;
    __shared__ int sm[4096];
    if (c <= 4096) {
        int n = 1;
        while (n < c) n <<= 1;
        for (int i = threadIdx.x; i < n; i += blockDim.x)
            sm[i] = (i < c) ? G[a + i] : 0x7fffffff;
        __syncthreads();
        for (int k = 2; k <= n; k <<= 1) {
            for (int j = k >> 1; j > 0; j >>= 1) {
                for (int i = threadIdx.x; i < n; i += blockDim.x) {
                    int l = i ^ j;
                    if (l > i) {
                        int vi = sm[i], vl = sm[l];
                        bool up = ((i & k) == 0);
                        if ((vi > vl) == up) { sm[i] = vl; sm[l] = vi; }
                    }
                }
                __syncthreads();
            }
        }
        for (int i = threadIdx.x; i < c; i += blockDim.x) G[a + i] = sm[i];
    } else {
        for (int it = 0; it < c; ++it) {
            int start = it & 1;
            for (int i = start + 2 * (int)threadIdx.x; i + 1 < c; i += 2 * (int)blockDim.x) {
                int x = G[a + i], y = G[a + i + 1];
                if (x > y) { G[a + i] = y; G[a + i + 1] = x; }
            }
            __syncthreads();
        }
    }
}

// ---------------- materialize desc-rank arrays P,E2 (one block per bin) ----------------
// For asc position i in [cum[t],cum[t+1]): desc-rank q = (i - cum[t]) + (N - cum[t+1]).
// idx_desc[q] = G[i].  P[q]=exp(log_h[G[i]]), E2[q]=events[G[i]].
__global__ __launch_bounds__(256) void pe_kernel(const float* __restrict__ log_h,
                                                 const int* __restrict__ events,
                                                 const int* __restrict__ G,
                                                 const int* __restrict__ cum,
                                                 float* __restrict__ P,
                                                 float* __restrict__ E2, int N) {
    int t = blockIdx.x;
    int a = cum[t], b = cum[t + 1];
    int qoff = N - b - a;  // q = i + qoff
    for (int i = a + threadIdx.x; i < b; i += blockDim.x) {
        int idx = G[i];
        int q = i + qoff;
        P[q]  = expf(log_h[idx]);
        E2[q] = (float)events[idx];
    }
}

// ---------------- segment sums: fully coalesced LDS float histograms ----------------
// expg[t] = sum_{j: dur[j]==t} P[j];  evs[t] = sum_{j: dur[j]==t} E2[j]
__global__ __launch_bounds__(512) void sums3(const int* __restrict__ dur,
                                             const float* __restrict__ P,
                                             const float* __restrict__ E2,
                                             float* __restrict__ expg_part,
                                             float* __restrict__ evs_part,
                                             int N, int chunk) {
    __shared__ float he[KSEG];
    __shared__ float hv[KSEG];
    for (int i = threadIdx.x; i < KSEG; i += blockDim.x) { he[i] = 0.f; hv[i] = 0.f; }
    __syncthreads();
    int b = blockIdx.x;
    int s = b * chunk, e = min(N, s + chunk);
    for (int j = s + threadIdx.x; j < e; j += blockDim.x) {
        int t = dur[j];
        atomicAdd(&he[t], P[j]);
        atomicAdd(&hv[t], E2[j]);
    }
    __syncthreads();
    for (int i = threadIdx.x; i < KSEG; i += blockDim.x) {
        expg_part[(size_t)b * KSEG + i] = he[i];
        evs_part[(size_t)b * KSEG + i] = hv[i];
    }
}

__global__ void reduce_sums(const float* __restrict__ expg_part,
                            const float* __restrict__ evs_part,
                            float* __restrict__ expg, float* __restrict__ evs, int B) {
    int t = blockIdx.x * blockDim.x + threadIdx.x;
    if (t >= KSEG) return;
    float a = 0.f, v = 0.f;
    for (int b = 0; b < B; ++b) {
        a += expg_part[(size_t)b * KSEG + t];
        v += evs_part[(size_t)b * KSEG + t];
    }
    expg[t] = a;
    evs[t] = v;
}

// ---------------- risk suffix-sum + baseline hazard + total events ----------------
__global__ void baseline_kernel(const float* __restrict__ expg, const float* __restrict__ evs,
                                float* __restrict__ base, float* __restrict__ ev_total, int K) {
    __shared__ float sm[1024];
    __shared__ float carry_s;
    int tid = threadIdx.x;
    if (tid == 0) carry_s = 0.f;
    float evloc = 0.f;
    __syncthreads();
    for (int b = 0; b < K; b += 1024) {
        int u = b + tid;
        int t = K - 1 - u;
        float v = 0.f, ev = 0.f;
        if (u < K) { v = expg[t]; ev = evs[t]; }
        evloc += ev;
        sm[tid] = v;
        __syncthreads();
        for (int off = 1; off < 1024; off <<= 1) {
            float x = (tid >= off) ? sm[tid - off] : 0.f;
            __syncthreads();
            sm[tid] += x;
            __syncthreads();
        }
        float carry = carry_s;
        if (u < K) {
            float risk = carry + sm[tid];  // inclusive suffix sum over bins >= t
            base[t] = (risk > 0.f) ? ev / risk : 0.f;
        }
        __syncthreads();
        if (tid == 1023) carry_s = carry + sm[1023];
        __syncthreads();
    }
    // total events = sum over bins (permutation-sum identity)
    sm[tid] = evloc;
    __syncthreads();
    for (int o = 512; o > 0; o >>= 1) {
        if (tid < o) sm[tid] += sm[tid + o];
        __syncthreads();
    }
    if (tid == 0) ev_total[0] = sm[0];
}

// ---------------- MSE, one block per bin: (base[t]*P[p] - E2[G[p]])^2 ----------------
__global__ __launch_bounds__(256) void mse3(const float* __restrict__ P,
                                            const float* __restrict__ E2,
                                            const int* __restrict__ G,
                                            const int* __restrict__ cum,
                                            const float* __restrict__ base,
                                            double* __restrict__ acc, int N) {
    int t = blockIdx.x;
    int a = cum[t], b = cum[t + 1];
    float bt = base[t];
    double s = 0.0;
    for (int p = a + threadIdx.x; p < b; p += blockDim.x) {
        float pred = bt * P[p];
        float d = pred - E2[G[p]];
        s += (double)d * (double)d;
    }
    __shared__ double sm[256];
    sm[threadIdx.x] = s;
    __syncthreads();
    for (int o = 128; o > 0; o >>= 1) {
        if ((int)threadIdx.x < o) sm[threadIdx.x] += sm[threadIdx.x + o];
        __syncthreads();
    }
    if (threadIdx.x == 0 && sm[0] != 0.0) atomicAdd(acc, sm[0]);
}

__global__ void final_kernel(const double* __restrict__ acc, const float* __restrict__ ev_total,
                             float* __restrict__ out, int N) {
    out[0] = (ev_total[0] == 0.f) ? 0.0f : (float)(*acc / (double)N);
}

extern "C" void kernel_launch(void* const* d_in, const int* in_sizes, int n_in,
                              void* d_out, int out_size, void* d_ws, size_t ws_size,
                              hipStream_t stream) {
    const float* log_h = (const float*)d_in[0];
    const int* dur     = (const int*)d_in[1];
    const int* events  = (const int*)d_in[2];
    int N = in_sizes[0];
    float* out = (float*)d_out;

    char* ws = (char*)d_ws;
    size_t off = 0;
    auto alloc = [&](size_t bytes) -> char* {
        char* p = ws + off;
        off = (off + bytes + 255) & ~(size_t)255;
        return p;
    };
    double* acc      = (double*)alloc(8);
    size_t zero_bytes = off;
    float*  ev_total  = (float*)alloc(4);
    int*    counts    = (int*)alloc(KSEG * 4);
    int*    cum       = (int*)alloc((KSEG + 1) * 4);
    float*  expg      = (float*)alloc(KSEG * 4);
    float*  evs       = (float*)alloc(KSEG * 4);
    float*  base      = (float*)alloc(KSEG * 4);
    int*    blockhist = (int*)alloc((size_t)NBLK * KSEG * 4);  // reused as expg_part
    int*    blockbase = (int*)alloc((size_t)NBLK * KSEG * 4);  // reused as evs_part
    int*    G         = (int*)alloc((size_t)N * 4);
    float*  P         = (float*)alloc((size_t)N * 4);
    float*  E2        = (float*)alloc((size_t)N * 4);
    (void)ws_size;

    int chunk = (N + NBLK - 1) / NBLK;

    hipMemsetAsync(d_ws, 0, zero_bytes, stream);

    hist_blocks<<<NBLK, 512, 0, stream>>>(dur, blockhist, N, chunk);
    colscan<<<(KSEG + 255) / 256, 256, 0, stream>>>(blockhist, blockbase, counts, NBLK);
    scan_kernel<<<1, 1024, 0, stream>>>(counts, cum, KSEG);
    scatter2<<<NBLK, 512, 0, stream>>>(dur, cum, blockbase, G, N, chunk);
    sort_groups<<<KSEG, 256, 0, stream>>>(G, cum);
    pe_kernel<<<KSEG, 256, 0, stream>>>(log_h, events, G, cum, P, E2, N);
    sums3<<<NBLK, 512, 0, stream>>>(dur, P, E2, (float*)blockhist, (float*)blockbase, N, chunk);
    reduce_sums<<<(KSEG + 255) / 256, 256, 0, stream>>>((const float*)blockhist,
                                                        (const float*)blockbase, expg, evs, NBLK);
    baseline_kernel<<<1, 1024, 0, stream>>>(expg, evs, base, ev_total, KSEG);
    mse3<<<KSEG, 256, 0, stream>>>(P, E2, G, cum, base, acc, N);
    final_kernel<<<1, 1, 0, stream>>>(acc, ev_total, out, N);
}

// Round 4
// 1113.474 us; speedup vs baseline: 3.7584x; 1.0216x over previous
//
#include <hip/hip_runtime.h>

#define KSEG 10000
#define NBLK 128   // counting-sort blocks (contiguous chunks)

typedef unsigned long long u64;
typedef unsigned int u32;
typedef unsigned char u8;

// ---------------- per-block LDS histogram of durations ----------------
__global__ __launch_bounds__(1024) void hist_blocks(const int* __restrict__ dur,
                                                    int* __restrict__ blockhist,
                                                    int N, int chunk) {
    __shared__ int h[KSEG];
    for (int i = threadIdx.x; i < KSEG; i += blockDim.x) h[i] = 0;
    __syncthreads();
    int b = blockIdx.x;
    int s = b * chunk, e = min(N, s + chunk);
    for (int j = s + threadIdx.x; j < e; j += blockDim.x)
        atomicAdd(&h[dur[j]], 1);
    __syncthreads();
    for (int i = threadIdx.x; i < KSEG; i += blockDim.x)
        blockhist[(size_t)b * KSEG + i] = h[i];
}

// ---------------- column scan: per-bin running sum over blocks ----------------
__global__ void colscan(const int* __restrict__ blockhist, int* __restrict__ blockbase,
                        int* __restrict__ counts, int B) {
    int t = blockIdx.x * blockDim.x + threadIdx.x;
    if (t >= KSEG) return;
    int run = 0;
    for (int b = 0; b < B; ++b) {
        int v = blockhist[(size_t)b * KSEG + t];
        blockbase[(size_t)b * KSEG + t] = run;
        run += v;
    }
    counts[t] = run;
}

// ---------------- exclusive prefix scan over K bins (single block) ----------------
__global__ void scan_kernel(const int* __restrict__ counts, int* __restrict__ cum, int K) {
    __shared__ int sm[1024];
    __shared__ int carry_s;
    int tid = threadIdx.x;
    if (tid == 0) carry_s = 0;
    __syncthreads();
    for (int base = 0; base < K; base += 1024) {
        int v = (base + tid < K) ? counts[base + tid] : 0;
        sm[tid] = v;
        __syncthreads();
        for (int off = 1; off < 1024; off <<= 1) {
            int t = (tid >= off) ? sm[tid - off] : 0;
            __syncthreads();
            sm[tid] += t;
            __syncthreads();
        }
        int carry = carry_s;
        if (base + tid < K) cum[base + tid] = carry + sm[tid] - v;  // exclusive
        __syncthreads();
        if (tid == 1023) carry_s = carry + sm[1023];
        __syncthreads();
    }
    if (tid == 0) cum[K] = carry_s;
}

// ---------------- scatter 8B records with LDS-only cursors ----------------
// record = ((j<<1 | ev) << 32) | float_bits(log_h[j]); sort by u64 == stable by j
__global__ __launch_bounds__(1024) void scatter2(const int* __restrict__ dur,
                                                 const float* __restrict__ log_h,
                                                 const int* __restrict__ events,
                                                 const int* __restrict__ cum,
                                                 const int* __restrict__ blockbase,
                                                 u64* __restrict__ R, int N, int chunk) {
    __shared__ int cur[KSEG];
    int b = blockIdx.x;
    for (int i = threadIdx.x; i < KSEG; i += blockDim.x)
        cur[i] = cum[i] + blockbase[(size_t)b * KSEG + i];
    __syncthreads();
    int s = b * chunk, e = min(N, s + chunk);
    for (int j = s + threadIdx.x; j < e; j += blockDim.x) {
        int t = dur[j];
        u32 hi = ((u32)j << 1) | (u32)events[j];
        u64 rec = ((u64)hi << 32) | (u64)__float_as_uint(log_h[j]);
        int pos = atomicAdd(&cur[t], 1);
        R[pos] = rec;
    }
}

// ---------------- per-bin sort (restores stability) fused with P/E2 emit ----------------
// After sort: asc pos g=a+li holds record of li-th smallest j in bin.
// desc-rank q = g + qoff, qoff = N - cum[t+1] - cum[t].
__global__ __launch_bounds__(256) void sort_pe(u64* __restrict__ R, const int* __restrict__ cum,
                                               float* __restrict__ P, u8* __restrict__ E2,
                                               int N) {
    int t = blockIdx.x;
    int a = cum[t], b = cum[t + 1];
    int c = b - a;
    if (c <= 0) return;
    int qoff = N - b - a;
    __shared__ u64 sm[4096];
    if (c <= 4096) {
        int n = 1;
        while (n < c) n <<= 1;
        for (int i = threadIdx.x; i < n; i += blockDim.x)
            sm[i] = (i < c) ? R[a + i] : ~(u64)0;
        __syncthreads();
        for (int k = 2; k <= n; k <<= 1) {
            for (int j = k >> 1; j > 0; j >>= 1) {
                for (int i = threadIdx.x; i < n; i += blockDim.x) {
                    int l = i ^ j;
                    if (l > i) {
                        u64 vi = sm[i], vl = sm[l];
                        bool up = ((i & k) == 0);
                        if ((vi > vl) == up) { sm[i] = vl; sm[l] = vi; }
                    }
                }
                __syncthreads();
            }
        }
        for (int i = threadIdx.x; i < c; i += blockDim.x) {
            u64 rec = sm[i];
            int g = a + i;
            R[g] = rec;
            int q = g + qoff;
            P[q] = expf(__uint_as_float((u32)rec));
            E2[q] = (u8)((rec >> 32) & 1u);
        }
    } else {
        // fallback: odd-even transposition in global (not expected for Poisson(800) bins)
        for (int it = 0; it < c; ++it) {
            int start = it & 1;
            for (int i = start + 2 * (int)threadIdx.x; i + 1 < c; i += 2 * (int)blockDim.x) {
                u64 x = R[a + i], y = R[a + i + 1];
                if (x > y) { R[a + i] = y; R[a + i + 1] = x; }
            }
            __syncthreads();
        }
        for (int i = threadIdx.x; i < c; i += blockDim.x) {
            u64 rec = R[a + i];
            int g = a + i;
            int q = g + qoff;
            P[q] = expf(__uint_as_float((u32)rec));
            E2[q] = (u8)((rec >> 32) & 1u);
        }
    }
}

// ---------------- segment sums: fully coalesced LDS float histograms ----------------
// expg[t] = sum_{j: dur[j]==t} P[j];  evs[t] = sum_{j: dur[j]==t} E2[j]
__global__ __launch_bounds__(512) void sums3(const int* __restrict__ dur,
                                             const float* __restrict__ P,
                                             const u8* __restrict__ E2,
                                             float* __restrict__ expg_part,
                                             float* __restrict__ evs_part,
                                             int N, int chunk) {
    __shared__ float he[KSEG];
    __shared__ float hv[KSEG];
    for (int i = threadIdx.x; i < KSEG; i += blockDim.x) { he[i] = 0.f; hv[i] = 0.f; }
    __syncthreads();
    int b = blockIdx.x;
    int s = b * chunk, e = min(N, s + chunk);
    for (int j = s + threadIdx.x; j < e; j += blockDim.x) {
        int t = dur[j];
        atomicAdd(&he[t], P[j]);
        float ev = (float)E2[j];
        if (ev != 0.f) atomicAdd(&hv[t], ev);
    }
    __syncthreads();
    for (int i = threadIdx.x; i < KSEG; i += blockDim.x) {
        expg_part[(size_t)b * KSEG + i] = he[i];
        evs_part[(size_t)b * KSEG + i] = hv[i];
    }
}

__global__ void reduce_sums(const float* __restrict__ expg_part,
                            const float* __restrict__ evs_part,
                            float* __restrict__ expg, float* __restrict__ evs, int B) {
    int t = blockIdx.x * blockDim.x + threadIdx.x;
    if (t >= KSEG) return;
    float a = 0.f, v = 0.f;
    for (int b = 0; b < B; ++b) {
        a += expg_part[(size_t)b * KSEG + t];
        v += evs_part[(size_t)b * KSEG + t];
    }
    expg[t] = a;
    evs[t] = v;
}

// ---------------- risk suffix-sum + baseline hazard + total events ----------------
__global__ void baseline_kernel(const float* __restrict__ expg, const float* __restrict__ evs,
                                float* __restrict__ base, float* __restrict__ ev_total, int K) {
    __shared__ float sm[1024];
    __shared__ float carry_s;
    int tid = threadIdx.x;
    if (tid == 0) carry_s = 0.f;
    float evloc = 0.f;
    __syncthreads();
    for (int b = 0; b < K; b += 1024) {
        int u = b + tid;
        int t = K - 1 - u;
        float v = 0.f, ev = 0.f;
        if (u < K) { v = expg[t]; ev = evs[t]; }
        evloc += ev;
        sm[tid] = v;
        __syncthreads();
        for (int off = 1; off < 1024; off <<= 1) {
            float x = (tid >= off) ? sm[tid - off] : 0.f;
            __syncthreads();
            sm[tid] += x;
            __syncthreads();
        }
        float carry = carry_s;
        if (u < K) {
            float risk = carry + sm[tid];  // inclusive suffix sum over bins >= t
            base[t] = (risk > 0.f) ? ev / risk : 0.f;
        }
        __syncthreads();
        if (tid == 1023) carry_s = carry + sm[1023];
        __syncthreads();
    }
    sm[tid] = evloc;
    __syncthreads();
    for (int o = 512; o > 0; o >>= 1) {
        if (tid < o) sm[tid] += sm[tid + o];
        __syncthreads();
    }
    if (tid == 0) ev_total[0] = sm[0];
}

// ---------------- MSE, one block per bin: (base[t]*P[p] - E2[j])^2, j = R[p].hi>>1 ----------------
__global__ __launch_bounds__(256) void mse3(const u64* __restrict__ R,
                                            const float* __restrict__ P,
                                            const u8* __restrict__ E2,
                                            const int* __restrict__ cum,
                                            const float* __restrict__ base,
                                            double* __restrict__ acc, int N) {
    int t = blockIdx.x;
    int a = cum[t], b = cum[t + 1];
    float bt = base[t];
    double s = 0.0;
    for (int p = a + threadIdx.x; p < b; p += blockDim.x) {
        u32 j = (u32)(R[p] >> 33);          // idx_asc[p]
        float pred = bt * P[p];
        float d = pred - (float)E2[j];      // E2[idx_asc[p]] == events[idx_desc[idx_asc[p]]]
        s += (double)d * (double)d;
    }
    __shared__ double sm[256];
    sm[threadIdx.x] = s;
    __syncthreads();
    for (int o = 128; o > 0; o >>= 1) {
        if ((int)threadIdx.x < o) sm[threadIdx.x] += sm[threadIdx.x + o];
        __syncthreads();
    }
    if (threadIdx.x == 0 && sm[0] != 0.0) atomicAdd(acc, sm[0]);
}

__global__ void final_kernel(const double* __restrict__ acc, const float* __restrict__ ev_total,
                             float* __restrict__ out, int N) {
    out[0] = (ev_total[0] == 0.f) ? 0.0f : (float)(*acc / (double)N);
}

extern "C" void kernel_launch(void* const* d_in, const int* in_sizes, int n_in,
                              void* d_out, int out_size, void* d_ws, size_t ws_size,
                              hipStream_t stream) {
    const float* log_h = (const float*)d_in[0];
    const int* dur     = (const int*)d_in[1];
    const int* events  = (const int*)d_in[2];
    int N = in_sizes[0];
    float* out = (float*)d_out;

    char* ws = (char*)d_ws;
    size_t off = 0;
    auto alloc = [&](size_t bytes) -> char* {
        char* p = ws + off;
        off = (off + bytes + 255) & ~(size_t)255;
        return p;
    };
    double* acc      = (double*)alloc(8);
    size_t zero_bytes = off;
    float*  ev_total  = (float*)alloc(4);
    int*    counts    = (int*)alloc(KSEG * 4);
    int*    cum       = (int*)alloc((KSEG + 1) * 4);
    float*  expg      = (float*)alloc(KSEG * 4);
    float*  evs       = (float*)alloc(KSEG * 4);
    float*  base      = (float*)alloc(KSEG * 4);
    int*    blockhist = (int*)alloc((size_t)NBLK * KSEG * 4);  // reused as expg_part
    int*    blockbase = (int*)alloc((size_t)NBLK * KSEG * 4);  // reused as evs_part
    u64*    R         = (u64*)alloc((size_t)N * 8);
    float*  P         = (float*)alloc((size_t)N * 4);
    u8*     E2        = (u8*)alloc((size_t)N);
    (void)ws_size;

    int chunk = (N + NBLK - 1) / NBLK;

    hipMemsetAsync(d_ws, 0, zero_bytes, stream);

    hist_blocks<<<NBLK, 1024, 0, stream>>>(dur, blockhist, N, chunk);
    colscan<<<(KSEG + 255) / 256, 256, 0, stream>>>(blockhist, blockbase, counts, NBLK);
    scan_kernel<<<1, 1024, 0, stream>>>(counts, cum, KSEG);
    scatter2<<<NBLK, 1024, 0, stream>>>(dur, log_h, events, cum, blockbase, R, N, chunk);
    sort_pe<<<KSEG, 256, 0, stream>>>(R, cum, P, E2, N);
    sums3<<<NBLK, 512, 0, stream>>>(dur, P, E2, (float*)blockhist, (float*)blockbase, N, chunk);
    reduce_sums<<<(KSEG + 255) / 256, 256, 0, stream>>>((const float*)blockhist,
                                                        (const float*)blockbase, expg, evs, NBLK);
    baseline_kernel<<<1, 1024, 0, stream>>>(expg, evs, base, ev_total, KSEG);
    mse3<<<KSEG, 256, 0, stream>>>(R, P, E2, cum, base, acc, N);
    final_kernel<<<1, 1, 0, stream>>>(acc, ev_total, out, N);
}

// Round 5
// 768.593 us; speedup vs baseline: 5.4449x; 1.4487x over previous
//
#include <hip/hip_runtime.h>

#define KSEG 10000
#define NBLK 256   // counting-sort blocks (contiguous chunks) == grid for streaming kernels

typedef unsigned long long u64;
typedef unsigned int u32;
typedef unsigned short u16;
typedef unsigned char u8;

// ---------------- per-block LDS histogram of durations ----------------
__global__ __launch_bounds__(1024) void hist_blocks(const int* __restrict__ dur,
                                                    int* __restrict__ blockhist,
                                                    int N, int chunk) {
    __shared__ int h[KSEG];
    for (int i = threadIdx.x; i < KSEG; i += blockDim.x) h[i] = 0;
    __syncthreads();
    int b = blockIdx.x;
    int s = b * chunk, e = min(N, s + chunk);
    for (int j = s + threadIdx.x; j < e; j += blockDim.x)
        atomicAdd(&h[dur[j]], 1);
    __syncthreads();
    for (int i = threadIdx.x; i < KSEG; i += blockDim.x)
        blockhist[(size_t)b * KSEG + i] = h[i];
}

// ---------------- column scan (in place): blockhist -> exclusive per-bin block bases ----------
// Also emits transposed u16 copy T[t*NBLK+b] for runsort_pe (per-bin run starts).
__global__ void colscan(int* __restrict__ blockhist, u16* __restrict__ T,
                        int* __restrict__ counts, int B) {
    int t = blockIdx.x * blockDim.x + threadIdx.x;
    if (t >= KSEG) return;
    int run = 0;
    for (int b = 0; b < B; ++b) {
        int v = blockhist[(size_t)b * KSEG + t];
        blockhist[(size_t)b * KSEG + t] = run;   // exclusive prefix (blockbase)
        T[(size_t)t * NBLK + b] = (u16)run;
        run += v;
    }
    counts[t] = run;
}

// ---------------- exclusive prefix scan over K bins (single block) ----------------
__global__ void scan_kernel(const int* __restrict__ counts, int* __restrict__ cum, int K) {
    __shared__ int sm[1024];
    __shared__ int carry_s;
    int tid = threadIdx.x;
    if (tid == 0) carry_s = 0;
    __syncthreads();
    for (int base = 0; base < K; base += 1024) {
        int v = (base + tid < K) ? counts[base + tid] : 0;
        sm[tid] = v;
        __syncthreads();
        for (int off = 1; off < 1024; off <<= 1) {
            int t = (tid >= off) ? sm[tid - off] : 0;
            __syncthreads();
            sm[tid] += t;
            __syncthreads();
        }
        int carry = carry_s;
        if (base + tid < K) cum[base + tid] = carry + sm[tid] - v;  // exclusive
        __syncthreads();
        if (tid == 1023) carry_s = carry + sm[1023];
        __syncthreads();
    }
    if (tid == 0) cum[K] = carry_s;
}

// ---------------- scatter 8B records with LDS-only cursors ----------------
// record = ((j<<1 | ev) << 32) | float_bits(log_h[j])
__global__ __launch_bounds__(1024) void scatter2(const int* __restrict__ dur,
                                                 const float* __restrict__ log_h,
                                                 const int* __restrict__ events,
                                                 const int* __restrict__ cum,
                                                 const int* __restrict__ blockbase,
                                                 u64* __restrict__ R, int N, int chunk) {
    __shared__ int cur[KSEG];
    int b = blockIdx.x;
    for (int i = threadIdx.x; i < KSEG; i += blockDim.x)
        cur[i] = cum[i] + blockbase[(size_t)b * KSEG + i];
    __syncthreads();
    int s = b * chunk, e = min(N, s + chunk);
    for (int j = s + threadIdx.x; j < e; j += blockDim.x) {
        int t = dur[j];
        u32 hi = ((u32)j << 1) | (u32)events[j];
        u64 rec = ((u64)hi << 32) | (u64)__float_as_uint(log_h[j]);
        int pos = atomicAdd(&cur[t], 1);
        R[pos] = rec;
    }
}

// ---------------- per-bin: sort tiny per-block runs + emit P/E2 ----------------
// Bin t is already partitioned in block order; only each (block,bin) run
// (mean len 800/NBLK ~= 3) is unordered. Thread w insertion-sorts run w in LDS.
// desc-rank q = g + qoff, qoff = N - cum[t+1] - cum[t].
__global__ __launch_bounds__(256) void runsort_pe(u64* __restrict__ R,
                                                  const int* __restrict__ cum,
                                                  const u16* __restrict__ T,
                                                  float* __restrict__ P, u8* __restrict__ E2,
                                                  int N) {
    int t = blockIdx.x;
    int a = cum[t], b = cum[t + 1];
    int c = b - a;
    if (c <= 0) return;
    int qoff = N - b - a;
    __shared__ u64 sm[4096];
    if (c <= 4096) {
        for (int i = threadIdx.x; i < c; i += blockDim.x)
            sm[i] = R[a + i];
        __syncthreads();
        int w = threadIdx.x;
        if (w < NBLK) {
            int rs = (int)T[(size_t)t * NBLK + w];
            int re = (w == NBLK - 1) ? c : (int)T[(size_t)t * NBLK + w + 1];
            for (int i = rs + 1; i < re; ++i) {
                u64 key = sm[i];
                int j = i - 1;
                while (j >= rs && sm[j] > key) { sm[j + 1] = sm[j]; --j; }
                sm[j + 1] = key;
            }
        }
        __syncthreads();
        for (int i = threadIdx.x; i < c; i += blockDim.x) {
            u64 rec = sm[i];
            int g = a + i;
            R[g] = rec;
            int q = g + qoff;
            P[q] = expf(__uint_as_float((u32)rec));
            E2[q] = (u8)((rec >> 32) & 1u);
        }
    } else {
        // fallback: odd-even transposition in global (never expected: bins ~Poisson(800))
        for (int it = 0; it < c; ++it) {
            int start = it & 1;
            for (int i = start + 2 * (int)threadIdx.x; i + 1 < c; i += 2 * (int)blockDim.x) {
                u64 x = R[a + i], y = R[a + i + 1];
                if (x > y) { R[a + i] = y; R[a + i + 1] = x; }
            }
            __syncthreads();
        }
        for (int i = threadIdx.x; i < c; i += blockDim.x) {
            u64 rec = R[a + i];
            int g = a + i;
            int q = g + qoff;
            P[q] = expf(__uint_as_float((u32)rec));
            E2[q] = (u8)((rec >> 32) & 1u);
        }
    }
}

// ---------------- segment sums: fully coalesced LDS histograms ----------------
// expg[t] = sum_{j: dur[j]==t} P[j];  evs[t] = count_{j: dur[j]==t} (E2[j]!=0)
__global__ __launch_bounds__(1024) void sums3(const int* __restrict__ dur,
                                              const float* __restrict__ P,
                                              const u8* __restrict__ E2,
                                              float* __restrict__ expg_part,
                                              u16* __restrict__ evs_part,
                                              int N, int chunk) {
    __shared__ float he[KSEG];
    __shared__ int hv[KSEG];
    for (int i = threadIdx.x; i < KSEG; i += blockDim.x) { he[i] = 0.f; hv[i] = 0; }
    __syncthreads();
    int b = blockIdx.x;
    int s = b * chunk, e = min(N, s + chunk);
    for (int j = s + threadIdx.x; j < e; j += blockDim.x) {
        int t = dur[j];
        atomicAdd(&he[t], P[j]);
        if (E2[j]) atomicAdd(&hv[t], 1);
    }
    __syncthreads();
    for (int i = threadIdx.x; i < KSEG; i += blockDim.x) {
        expg_part[(size_t)b * KSEG + i] = he[i];
        evs_part[(size_t)b * KSEG + i] = (u16)hv[i];
    }
}

__global__ void reduce_sums(const float* __restrict__ expg_part,
                            const u16* __restrict__ evs_part,
                            float* __restrict__ expg, float* __restrict__ evs, int B) {
    int t = blockIdx.x * blockDim.x + threadIdx.x;
    if (t >= KSEG) return;
    float a = 0.f;
    int v = 0;
    for (int b = 0; b < B; ++b) {
        a += expg_part[(size_t)b * KSEG + t];
        v += (int)evs_part[(size_t)b * KSEG + t];
    }
    expg[t] = a;
    evs[t] = (float)v;
}

// ---------------- risk suffix-sum + baseline hazard + total events ----------------
__global__ void baseline_kernel(const float* __restrict__ expg, const float* __restrict__ evs,
                                float* __restrict__ base, float* __restrict__ ev_total, int K) {
    __shared__ float sm[1024];
    __shared__ float carry_s;
    int tid = threadIdx.x;
    if (tid == 0) carry_s = 0.f;
    float evloc = 0.f;
    __syncthreads();
    for (int b = 0; b < K; b += 1024) {
        int u = b + tid;
        int t = K - 1 - u;
        float v = 0.f, ev = 0.f;
        if (u < K) { v = expg[t]; ev = evs[t]; }
        evloc += ev;
        sm[tid] = v;
        __syncthreads();
        for (int off = 1; off < 1024; off <<= 1) {
            float x = (tid >= off) ? sm[tid - off] : 0.f;
            __syncthreads();
            sm[tid] += x;
            __syncthreads();
        }
        float carry = carry_s;
        if (u < K) {
            float risk = carry + sm[tid];  // inclusive suffix sum over bins >= t
            base[t] = (risk > 0.f) ? ev / risk : 0.f;
        }
        __syncthreads();
        if (tid == 1023) carry_s = carry + sm[1023];
        __syncthreads();
    }
    sm[tid] = evloc;
    __syncthreads();
    for (int o = 512; o > 0; o >>= 1) {
        if (tid < o) sm[tid] += sm[tid + o];
        __syncthreads();
    }
    if (tid == 0) ev_total[0] = sm[0];
}

// ---------------- MSE, one block per bin: (base[t]*P[p] - E2[j])^2, j = R[p].hi>>1 ----------------
__global__ __launch_bounds__(256) void mse3(const u64* __restrict__ R,
                                            const float* __restrict__ P,
                                            const u8* __restrict__ E2,
                                            const int* __restrict__ cum,
                                            const float* __restrict__ base,
                                            double* __restrict__ acc, int N) {
    int t = blockIdx.x;
    int a = cum[t], b = cum[t + 1];
    float bt = base[t];
    double s = 0.0;
    for (int p = a + threadIdx.x; p < b; p += blockDim.x) {
        u32 j = (u32)(R[p] >> 33);          // idx_asc[p]
        float pred = bt * P[p];
        float d = pred - (float)E2[j];      // E2[idx_asc[p]] == events[idx_desc[idx_asc[p]]]
        s += (double)d * (double)d;
    }
    __shared__ double sm[256];
    sm[threadIdx.x] = s;
    __syncthreads();
    for (int o = 128; o > 0; o >>= 1) {
        if ((int)threadIdx.x < o) sm[threadIdx.x] += sm[threadIdx.x + o];
        __syncthreads();
    }
    if (threadIdx.x == 0 && sm[0] != 0.0) atomicAdd(acc, sm[0]);
}

__global__ void final_kernel(const double* __restrict__ acc, const float* __restrict__ ev_total,
                             float* __restrict__ out, int N) {
    out[0] = (ev_total[0] == 0.f) ? 0.0f : (float)(*acc / (double)N);
}

extern "C" void kernel_launch(void* const* d_in, const int* in_sizes, int n_in,
                              void* d_out, int out_size, void* d_ws, size_t ws_size,
                              hipStream_t stream) {
    const float* log_h = (const float*)d_in[0];
    const int* dur     = (const int*)d_in[1];
    const int* events  = (const int*)d_in[2];
    int N = in_sizes[0];
    float* out = (float*)d_out;

    char* ws = (char*)d_ws;
    size_t off = 0;
    auto alloc = [&](size_t bytes) -> char* {
        char* p = ws + off;
        off = (off + bytes + 255) & ~(size_t)255;
        return p;
    };
    double* acc      = (double*)alloc(8);
    size_t zero_bytes = off;
    float*  ev_total  = (float*)alloc(4);
    int*    counts    = (int*)alloc(KSEG * 4);
    int*    cum       = (int*)alloc((KSEG + 1) * 4);
    float*  expg      = (float*)alloc(KSEG * 4);
    float*  evs       = (float*)alloc(KSEG * 4);
    float*  base      = (float*)alloc(KSEG * 4);
    int*    blockhist = (int*)alloc((size_t)NBLK * KSEG * 4);  // -> blockbase; reused as expg_part
    u16*    T         = (u16*)alloc((size_t)KSEG * NBLK * 2);  // run starts; reused as evs_part
    u64*    R         = (u64*)alloc((size_t)N * 8);
    float*  P         = (float*)alloc((size_t)N * 4);
    u8*     E2        = (u8*)alloc((size_t)N);
    (void)ws_size;

    int chunk = (N + NBLK - 1) / NBLK;

    hipMemsetAsync(d_ws, 0, zero_bytes, stream);

    hist_blocks<<<NBLK, 1024, 0, stream>>>(dur, blockhist, N, chunk);
    colscan<<<(KSEG + 255) / 256, 256, 0, stream>>>(blockhist, T, counts, NBLK);
    scan_kernel<<<1, 1024, 0, stream>>>(counts, cum, KSEG);
    scatter2<<<NBLK, 1024, 0, stream>>>(dur, log_h, events, cum, blockhist, R, N, chunk);
    runsort_pe<<<KSEG, 256, 0, stream>>>(R, cum, T, P, E2, N);
    sums3<<<NBLK, 1024, 0, stream>>>(dur, P, E2, (float*)blockhist, (u16*)T, N, chunk);
    reduce_sums<<<(KSEG + 255) / 256, 256, 0, stream>>>((const float*)blockhist,
                                                        (const u16*)T, expg, evs, NBLK);
    baseline_kernel<<<1, 1024, 0, stream>>>(expg, evs, base, ev_total, KSEG);
    mse3<<<KSEG, 256, 0, stream>>>(R, P, E2, cum, base, acc, N);
    final_kernel<<<1, 1, 0, stream>>>(acc, ev_total, out, N);
}